// Round 9
// baseline (173.973 us; speedup 1.0000x reference)
//
#include <hip/hip_runtime.h>
#include <hip/hip_bf16.h>

typedef __bf16 bf16_t;
typedef __bf16 bf16x8 __attribute__((ext_vector_type(8)));
typedef __bf16 bf16x4 __attribute__((ext_vector_type(4)));
typedef float  f32x4  __attribute__((ext_vector_type(4)));

#define D 128
#define LDS_ELEMS (4*16384 + 4*2048)   // 4 weight slices + 4 wave chunks = 147456 B

// LDS element-index swizzle: XOR multiples of 8 elems (16B) keep 8-elem groups intact.
__device__ __forceinline__ int swz(int r, int c) {
    return (r * D + c) ^ ((r & 7) << 3);
}

// prep: blocks [0,xb) convert x -> bf16; blocks [xb, xb+256) build 4 slice-major
// transposed weight tiles ws[s][n][k] (s<3: W1^T slice, s==3: W2^T).
__global__ void prep_kernel(const float* __restrict__ W1,
                            const float* __restrict__ W2,
                            const float* __restrict__ x,
                            bf16_t* __restrict__ ws,
                            bf16_t* __restrict__ xh,
                            int xb, int nx) {
    int b = blockIdx.x;
    if (b < xb) {
        int t = b * 256 + threadIdx.x;
        if (t * 8 + 7 < nx) {
            f32x4 lo = *(const f32x4*)(x + t * 8);
            f32x4 hi = *(const f32x4*)(x + t * 8 + 4);
            bf16x8 v = { (bf16_t)lo.x,(bf16_t)lo.y,(bf16_t)lo.z,(bf16_t)lo.w,
                         (bf16_t)hi.x,(bf16_t)hi.y,(bf16_t)hi.z,(bf16_t)hi.w };
            *(bf16x8*)(xh + t * 8) = v;
        }
    } else {
        int t = (b - xb) * 256 + threadIdx.x;
        int s = t >> 14, r = t & 16383;
        int n = r >> 7, k = r & 127;
        float v = (s < 3) ? W1[(s * 128 + k) * 128 + n] : W2[k * 128 + n];
        ws[t] = (bf16_t)v;
    }
}

__global__ __launch_bounds__(256, 1)
void fused_edge_mlp_kernel(const bf16_t* __restrict__ xh,
                           const float* __restrict__ ea,
                           const int* __restrict__ ei,
                           const bf16_t* __restrict__ ws,
                           const float* __restrict__ b1,
                           const float* __restrict__ b2,
                           float* __restrict__ out,
                           int E) {
    extern __shared__ __align__(16) bf16_t lds[];   // [4][128][128] weights + [4][16][128] chunks

    const int tid  = threadIdx.x;
    const int lane = tid & 63;
    const int wv   = tid >> 6;
    const int col0 = lane & 15;
    const int krow = lane >> 4;           // 0..3
    const int l31  = lane & 31;
    const int half = lane >> 5;           // 0/1
    const int gr   = lane >> 4;           // gather row-in-quad
    const int gc   = (lane & 15) * 8;     // gather element offset (16B per lane)
    const int brow = tid >> 4;            // weight staging row 0..15
    const int bslot = (tid & 15) * 8;

    bf16_t* Ach = lds + 65536 + wv * 2048;    // this wave's 16x128 chunk

    const int totg = (E + 15) >> 4;           // 16-edge groups
    const int gstr = gridDim.x * 4;
    int g = blockIdx.x * 4 + wv;

    bf16x8 bufS[4], bufD[4];
    f32x4  eaB[8];
    int sidx = 0, didx = 0, sidxN = 0, didxN = 0;

    // ---- first-group loads issued before weight staging (overlap) ----
    if (g < totg) {
        int er = min(g * 16 + col0, E - 1);
        sidx = ei[er];  didx = ei[E + er];
#pragma unroll
        for (int j = 0; j < 4; j++) { int gi = __shfl(sidx, j*4 + gr); bufS[j] = *(const bf16x8*)(xh + gi * D + gc); }
#pragma unroll
        for (int j = 0; j < 4; j++) { int gi = __shfl(didx, j*4 + gr); bufD[j] = *(const bf16x8*)(xh + gi * D + gc); }
#pragma unroll
        for (int j = 0; j < 8; j++) { int e2 = min(g*16 + j*2 + half, E - 1); eaB[j] = *(const f32x4*)(ea + (long long)e2 * D + l31 * 4); }
        int gn = g + gstr;
        if (gn < totg) { int e3 = min(gn*16 + col0, E - 1); sidxN = ei[e3]; didxN = ei[E + e3]; }
    }

    // ---- stage all 4 weight slices into LDS (once) ----
#pragma unroll
    for (int s = 0; s < 4; s++) {
        const bf16_t* base = ws + s * 16384;
#pragma unroll
        for (int j = 0; j < 8; j++) {
            bf16x8 v = *(const bf16x8*)(base + (j * 16 + brow) * 128 + bslot);
            *(bf16x8*)&lds[s * 16384 + swz(j * 16 + brow, bslot)] = v;
        }
    }
    float bias1[8], bias2[8];
#pragma unroll
    for (int n = 0; n < 8; n++) { bias1[n] = b1[n*16 + col0]; bias2[n] = b2[n*16 + col0]; }

    __syncthreads();   // the ONLY barrier

    f32x4 acc[8];

#define MFMA_PHASE(S)                                                                    \
    _Pragma("unroll")                                                                    \
    for (int kk = 0; kk < 4; kk++) {                                                     \
        bf16x8 a = *(const bf16x8*)&Ach[swz(col0, kk*32 + krow*8)];                      \
        _Pragma("unroll")                                                                \
        for (int n = 0; n < 8; n++) {                                                    \
            bf16x8 b = *(const bf16x8*)&lds[(S)*16384 + swz(n*16 + col0, kk*32 + krow*8)];\
            acc[n] = __builtin_amdgcn_mfma_f32_16x16x32_bf16(a, b, acc[n], 0, 0, 0);     \
        }                                                                                \
    }

    // ---- steady loop: zero barriers, loads always in flight ----
    while (g < totg) {
        const int gn = g + gstr;
#pragma unroll
        for (int n = 0; n < 8; n++) acc[n] = (f32x4){0.f, 0.f, 0.f, 0.f};

        // src -> chunk (waits on bufS loads only)
#pragma unroll
        for (int j = 0; j < 4; j++) *(bf16x8*)&Ach[swz(j*4 + gr, gc)] = bufS[j];
        MFMA_PHASE(0)

        // dst -> chunk (per-wave in-order LDS: ordered after PH0's reads)
#pragma unroll
        for (int j = 0; j < 4; j++) *(bf16x8*)&Ach[swz(j*4 + gr, gc)] = bufD[j];
        // issue next group's src/dst gathers (fly across PH1..PH3, no drain)
        if (gn < totg) {
#pragma unroll
            for (int j = 0; j < 4; j++) { int gi = __shfl(sidxN, j*4 + gr); bufS[j] = *(const bf16x8*)(xh + gi * D + gc); }
#pragma unroll
            for (int j = 0; j < 4; j++) { int gi = __shfl(didxN, j*4 + gr); bufD[j] = *(const bf16x8*)(xh + gi * D + gc); }
        }
        MFMA_PHASE(1)

        // ea -> chunk; issue next ea; prefetch idx two groups ahead
#pragma unroll
        for (int j = 0; j < 8; j++) {
            f32x4 v = eaB[j];
            bf16x4 hv = { (bf16_t)v.x, (bf16_t)v.y, (bf16_t)v.z, (bf16_t)v.w };
            *(bf16x4*)&Ach[swz(j*2 + half, l31 * 4)] = hv;
        }
        if (gn < totg) {
#pragma unroll
            for (int j = 0; j < 8; j++) { int e2 = min(gn*16 + j*2 + half, E - 1); eaB[j] = *(const f32x4*)(ea + (long long)e2 * D + l31 * 4); }
            int g2 = gn + gstr;
            if (g2 < totg) { int e3 = min(g2*16 + col0, E - 1); sidxN = ei[e3]; didxN = ei[E + e3]; }
        }
        MFMA_PHASE(2)

        // h = relu(acc + b1) -> chunk; reset acc
#pragma unroll
        for (int n = 0; n < 8; n++)
#pragma unroll
            for (int ri = 0; ri < 4; ri++) {
                float hv = fmaxf(acc[n][ri] + bias1[n], 0.f);
                Ach[swz(krow*4 + ri, n*16 + col0)] = (bf16_t)hv;
            }
#pragma unroll
        for (int n = 0; n < 8; n++) acc[n] = (f32x4){0.f, 0.f, 0.f, 0.f};
        MFMA_PHASE(3)

        // store out = relu(acc + b2)
#pragma unroll
        for (int n = 0; n < 8; n++)
#pragma unroll
            for (int ri = 0; ri < 4; ri++) {
                int e = g*16 + krow*4 + ri;
                if (e < E) out[(long long)e * D + n*16 + col0] = fmaxf(acc[n][ri] + bias2[n], 0.f);
            }
        g = gn;
    }
#undef MFMA_PHASE
}

extern "C" void kernel_launch(void* const* d_in, const int* in_sizes, int n_in,
                              void* d_out, int out_size, void* d_ws, size_t ws_size,
                              hipStream_t stream) {
    const float* x  = (const float*)d_in[0];
    const float* ea = (const float*)d_in[1];
    const int*   ei = (const int*)d_in[2];
    const float* W1 = (const float*)d_in[3];
    const float* b1 = (const float*)d_in[4];
    const float* W2 = (const float*)d_in[5];
    const float* b2 = (const float*)d_in[6];
    float* out = (float*)d_out;

    const int E  = in_sizes[1] / D;        // 400000
    const int nx = in_sizes[0];            // 50000*128

    bf16_t* wsl = (bf16_t*)d_ws;                 // 128 KB: 4 slice-major weight tiles
    bf16_t* xh  = (bf16_t*)d_ws + 4 * 16384;     // 12.8 MB: x in bf16

    const int xb = (nx + 256*8 - 1) / (256*8);   // 3125
    prep_kernel<<<xb + 256, 256, 0, stream>>>(W1, W2, x, wsl, xh, xb, nx);

    hipFuncSetAttribute(reinterpret_cast<const void*>(fused_edge_mlp_kernel),
                        hipFuncAttributeMaxDynamicSharedMemorySize,
                        LDS_ELEMS * (int)sizeof(bf16_t));
    fused_edge_mlp_kernel<<<256, 256, LDS_ELEMS * sizeof(bf16_t), stream>>>(
        xh, ea, ei, wsl, b1, b2, out, E);
}

// Round 10
// 150.133 us; speedup vs baseline: 1.1588x; 1.1588x over previous
//
#include <hip/hip_runtime.h>
#include <hip/hip_bf16.h>

typedef __bf16 bf16_t;
typedef __bf16 bf16x8 __attribute__((ext_vector_type(8)));
typedef __bf16 bf16x4 __attribute__((ext_vector_type(4)));
typedef float  f32x4  __attribute__((ext_vector_type(4)));

#define D 128
#define LDS_BYTES 131072   // 64KB weights (2 slices) + 8 waves x 8KB chunks

// LDS element-index swizzle: XOR multiples of 8 elems (16B) keep 8-elem groups intact.
__device__ __forceinline__ int swz(int r, int c) {
    return (r * D + c) ^ ((r & 7) << 3);
}

// 4 transposed bf16 weight slices: s<3: ws[s][n][k]=W1[(s*128+k)*128+n]; s==3: W2[k*128+n]
__global__ void prep_weights_kernel(const float* __restrict__ W1,
                                    const float* __restrict__ W2,
                                    bf16_t* __restrict__ ws) {
    int t = blockIdx.x * 256 + threadIdx.x;
    int s = t >> 14, r = t & 16383;
    int n = r >> 7, k = r & 127;
    float v = (s < 3) ? W1[(s * 128 + k) * 128 + n] : W2[k * 128 + n];
    ws[t] = (bf16_t)v;
}

// u = x·W1a + b1, v = x·W1b   (bf16 row-major outputs, gather-ready)
__global__ __launch_bounds__(512, 2)
void uv_kernel(const float* __restrict__ x, const bf16_t* __restrict__ ws,
               const float* __restrict__ b1, bf16_t* __restrict__ u,
               bf16_t* __restrict__ v, int N) {
    extern __shared__ __align__(16) bf16_t lds[];
    const int tid = threadIdx.x, lane = tid & 63, wv = tid >> 6;
    const int col0 = lane & 15, krow = lane >> 4, l31 = lane & 31, half = lane >> 5;
    const int gr = lane >> 4, gc = (lane & 15) * 8;
    const int n0 = blockIdx.x * 256 + wv * 32;
    bf16_t* Ach = lds + 32768 + wv * 4096;

    f32x4 xb[16];
#pragma unroll
    for (int j = 0; j < 16; j++) {
        int node = min(n0 + j * 2 + half, N - 1);
        xb[j] = *(const f32x4*)(x + (long long)node * D + l31 * 4);
    }
    // stage W1a^T (slice0), W1b^T (slice1)
#pragma unroll
    for (int s = 0; s < 2; s++)
#pragma unroll
        for (int j = 0; j < 4; j++) {
            int row = j * 32 + (tid >> 4), slot = (tid & 15) * 8;
            bf16x8 w = *(const bf16x8*)(ws + s * 16384 + row * 128 + slot);
            *(bf16x8*)&lds[s * 16384 + swz(row, slot)] = w;
        }
    float bias1[8];
#pragma unroll
    for (int n = 0; n < 8; n++) bias1[n] = b1[n * 16 + col0];
    // x -> my chunk (wave-private, pre-barrier ok)
#pragma unroll
    for (int j = 0; j < 16; j++) {
        f32x4 vv = xb[j];
        bf16x4 hv = { (bf16_t)vv.x, (bf16_t)vv.y, (bf16_t)vv.z, (bf16_t)vv.w };
        *(bf16x4*)&Ach[swz(j * 2 + half, l31 * 4)] = hv;
    }
    __syncthreads();

    f32x4 aU[2][8], aV[2][8];
#pragma unroll
    for (int m = 0; m < 2; m++)
#pragma unroll
        for (int n = 0; n < 8; n++) { aU[m][n] = (f32x4){0,0,0,0}; aV[m][n] = (f32x4){0,0,0,0}; }
#pragma unroll
    for (int kk = 0; kk < 4; kk++) {
        bf16x8 a0 = *(const bf16x8*)&Ach[swz(col0, kk*32 + krow*8)];
        bf16x8 a1 = *(const bf16x8*)&Ach[swz(16 + col0, kk*32 + krow*8)];
#pragma unroll
        for (int n = 0; n < 8; n++) {
            bf16x8 bU = *(const bf16x8*)&lds[swz(n*16 + col0, kk*32 + krow*8)];
            bf16x8 bV = *(const bf16x8*)&lds[16384 + swz(n*16 + col0, kk*32 + krow*8)];
            aU[0][n] = __builtin_amdgcn_mfma_f32_16x16x32_bf16(a0, bU, aU[0][n], 0,0,0);
            aU[1][n] = __builtin_amdgcn_mfma_f32_16x16x32_bf16(a1, bU, aU[1][n], 0,0,0);
            aV[0][n] = __builtin_amdgcn_mfma_f32_16x16x32_bf16(a0, bV, aV[0][n], 0,0,0);
            aV[1][n] = __builtin_amdgcn_mfma_f32_16x16x32_bf16(a1, bV, aV[1][n], 0,0,0);
        }
    }
    // u writeback via chunk transpose (C-space u16 writes -> row b128 reads -> coalesced stores)
#pragma unroll
    for (int m = 0; m < 2; m++)
#pragma unroll
        for (int n = 0; n < 8; n++)
#pragma unroll
            for (int ri = 0; ri < 4; ri++)
                Ach[swz(m*16 + krow*4 + ri, n*16 + col0)] = (bf16_t)(aU[m][n][ri] + bias1[n]);
#pragma unroll
    for (int j = 0; j < 8; j++) {
        int r = j * 4 + gr, node = n0 + r;
        if (node < N) *(bf16x8*)(u + (long long)node * D + gc) = *(const bf16x8*)&Ach[swz(r, gc)];
    }
#pragma unroll
    for (int m = 0; m < 2; m++)
#pragma unroll
        for (int n = 0; n < 8; n++)
#pragma unroll
            for (int ri = 0; ri < 4; ri++)
                Ach[swz(m*16 + krow*4 + ri, n*16 + col0)] = (bf16_t)(aV[m][n][ri]);
#pragma unroll
    for (int j = 0; j < 8; j++) {
        int r = j * 4 + gr, node = n0 + r;
        if (node < N) *(bf16x8*)(v + (long long)node * D + gc) = *(const bf16x8*)&Ach[swz(r, gc)];
    }
}

// out = relu( relu(ea·W1c + u[src] + v[dst]) · W2 + b2 )
__global__ __launch_bounds__(512, 2)
void edge_kernel(const bf16_t* __restrict__ u, const bf16_t* __restrict__ v,
                 const float* __restrict__ ea, const int* __restrict__ ei,
                 const bf16_t* __restrict__ ws, const float* __restrict__ b2,
                 float* __restrict__ out, int E) {
    extern __shared__ __align__(16) bf16_t lds[];   // [2][128][128] W1c,W2 + [8][32][128]
    const int tid = threadIdx.x, lane = tid & 63, wv = tid >> 6;
    const int col0 = lane & 15, krow = lane >> 4, l31 = lane & 31, half = lane >> 5;
    const int gr = lane >> 4, gc = (lane & 15) * 8;
    const int g0 = blockIdx.x * 256 + wv * 32;
    bf16_t* Ach = lds + 32768 + wv * 4096;

    const int er = min(g0 + l31, E - 1);
    const int sidx = ei[er];
    const int didx = ei[E + er];

    // issue ea streams (16 x 1KB-coalesced wave instrs)
    f32x4 eaB[16];
#pragma unroll
    for (int j = 0; j < 16; j++) {
        int e = min(g0 + j * 2 + half, E - 1);
        eaB[j] = *(const f32x4*)(ea + (long long)e * D + l31 * 4);
    }
    // stage W1c (slice2), W2 (slice3) -> Wlds[0], Wlds[1]
#pragma unroll
    for (int s = 0; s < 2; s++)
#pragma unroll
        for (int j = 0; j < 4; j++) {
            int row = j * 32 + (tid >> 4), slot = (tid & 15) * 8;
            bf16x8 w = *(const bf16x8*)(ws + (2 + s) * 16384 + row * 128 + slot);
            *(bf16x8*)&lds[s * 16384 + swz(row, slot)] = w;
        }
    float bias2[8];
#pragma unroll
    for (int n = 0; n < 8; n++) bias2[n] = b2[n * 16 + col0];
    // ea -> my chunk (waits only ea loads; frees eaB regs)
#pragma unroll
    for (int j = 0; j < 16; j++) {
        f32x4 vv = eaB[j];
        bf16x4 hv = { (bf16_t)vv.x, (bf16_t)vv.y, (bf16_t)vv.z, (bf16_t)vv.w };
        *(bf16x4*)&Ach[swz(j * 2 + half, l31 * 4)] = hv;
    }
    __syncthreads();   // weights ready (the only barrier)

    // issue u/v gathers (256B rows, 4 rows/instr); they fly during A1's MFMA
    bf16x8 bufU[8], bufV[8];
#pragma unroll
    for (int j = 0; j < 8; j++) { int gi = __shfl(sidx, j * 4 + gr); bufU[j] = *(const bf16x8*)(u + (long long)gi * D + gc); }
#pragma unroll
    for (int j = 0; j < 8; j++) { int gi = __shfl(didx, j * 4 + gr); bufV[j] = *(const bf16x8*)(v + (long long)gi * D + gc); }

    f32x4 acc[2][8];
#pragma unroll
    for (int m = 0; m < 2; m++)
#pragma unroll
        for (int n = 0; n < 8; n++) acc[m][n] = (f32x4){0,0,0,0};

    // ---- A1: ea · W1c ----
#pragma unroll
    for (int kk = 0; kk < 4; kk++) {
        bf16x8 a0 = *(const bf16x8*)&Ach[swz(col0, kk*32 + krow*8)];
        bf16x8 a1 = *(const bf16x8*)&Ach[swz(16 + col0, kk*32 + krow*8)];
#pragma unroll
        for (int n = 0; n < 8; n++) {
            bf16x8 b = *(const bf16x8*)&lds[swz(n*16 + col0, kk*32 + krow*8)];
            acc[0][n] = __builtin_amdgcn_mfma_f32_16x16x32_bf16(a0, b, acc[0][n], 0,0,0);
            acc[1][n] = __builtin_amdgcn_mfma_f32_16x16x32_bf16(a1, b, acc[1][n], 0,0,0);
        }
    }

    // s = u[src] + v[dst]  -> chunk (row space; b1 already folded into u)
#pragma unroll
    for (int j = 0; j < 8; j++) {
        bf16x8 su = bufU[j], sv = bufV[j], sr;
#pragma unroll
        for (int t = 0; t < 8; t++) sr[t] = (bf16_t)((float)su[t] + (float)sv[t]);
        *(bf16x8*)&Ach[swz(j * 4 + gr, gc)] = sr;
    }
    // h = relu(acc + s) in C-space, written back to chunk as A2's operand
#pragma unroll
    for (int m = 0; m < 2; m++)
#pragma unroll
        for (int n = 0; n < 8; n++)
#pragma unroll
            for (int ri = 0; ri < 4; ri++) {
                int row = m*16 + krow*4 + ri, col = n*16 + col0;
                float sval = (float)Ach[swz(row, col)];
                float hv = fmaxf(acc[m][n][ri] + sval, 0.f);
                Ach[swz(row, col)] = (bf16_t)hv;
            }
#pragma unroll
    for (int m = 0; m < 2; m++)
#pragma unroll
        for (int n = 0; n < 8; n++) acc[m][n] = (f32x4){0,0,0,0};

    // ---- A2: h · W2 ----
#pragma unroll
    for (int kk = 0; kk < 4; kk++) {
        bf16x8 a0 = *(const bf16x8*)&Ach[swz(col0, kk*32 + krow*8)];
        bf16x8 a1 = *(const bf16x8*)&Ach[swz(16 + col0, kk*32 + krow*8)];
#pragma unroll
        for (int n = 0; n < 8; n++) {
            bf16x8 b = *(const bf16x8*)&lds[16384 + swz(n*16 + col0, kk*32 + krow*8)];
            acc[0][n] = __builtin_amdgcn_mfma_f32_16x16x32_bf16(a0, b, acc[0][n], 0,0,0);
            acc[1][n] = __builtin_amdgcn_mfma_f32_16x16x32_bf16(a1, b, acc[1][n], 0,0,0);
        }
    }

    // epilogue: out = relu(acc + b2)
#pragma unroll
    for (int m = 0; m < 2; m++)
#pragma unroll
        for (int n = 0; n < 8; n++)
#pragma unroll
            for (int ri = 0; ri < 4; ri++) {
                int e = g0 + m*16 + krow*4 + ri;
                if (e < E) out[(long long)e * D + n*16 + col0] = fmaxf(acc[m][n][ri] + bias2[n], 0.f);
            }
}

extern "C" void kernel_launch(void* const* d_in, const int* in_sizes, int n_in,
                              void* d_out, int out_size, void* d_ws, size_t ws_size,
                              hipStream_t stream) {
    const float* x  = (const float*)d_in[0];
    const float* ea = (const float*)d_in[1];
    const int*   ei = (const int*)d_in[2];
    const float* W1 = (const float*)d_in[3];
    const float* b1 = (const float*)d_in[4];
    const float* W2 = (const float*)d_in[5];
    const float* b2 = (const float*)d_in[6];
    float* out = (float*)d_out;

    const int E = in_sizes[1] / D;      // 400000
    const int N = in_sizes[0] / D;      // 50000

    bf16_t* wsl = (bf16_t*)d_ws;                  // 128 KB: 4 transposed weight slices
    bf16_t* uu  = wsl + 4 * 16384;                // N*128 bf16
    bf16_t* vv  = uu + (size_t)N * D;             // N*128 bf16

    prep_weights_kernel<<<256, 256, 0, stream>>>(W1, W2, wsl);

    hipFuncSetAttribute(reinterpret_cast<const void*>(uv_kernel),
                        hipFuncAttributeMaxDynamicSharedMemorySize, LDS_BYTES);
    hipFuncSetAttribute(reinterpret_cast<const void*>(edge_kernel),
                        hipFuncAttributeMaxDynamicSharedMemorySize, LDS_BYTES);

    uv_kernel<<<(N + 255) / 256, 512, LDS_BYTES, stream>>>(x, wsl, b1, uu, vv, N);

    edge_kernel<<<(E + 255) / 256, 512, LDS_BYTES, stream>>>(uu, vv, ea, ei, wsl, b2, out, E);
}

// Round 11
// 135.456 us; speedup vs baseline: 1.2844x; 1.1084x over previous
//
#include <hip/hip_runtime.h>
#include <hip/hip_bf16.h>

typedef __bf16 bf16_t;
typedef __bf16 bf16x8 __attribute__((ext_vector_type(8)));
typedef __bf16 bf16x4 __attribute__((ext_vector_type(4)));
typedef float  f32x4  __attribute__((ext_vector_type(4)));

#define D 128
#define UV_LDS   131072   // uv_kernel: 64KB weights + 8 x 8KB chunks
#define EDGE_LDS 98304    // edge_kernel: 64KB weights + 8 x 4KB chunks

// LDS element-index swizzle: XOR multiples of 8 elems (16B) keep 8-elem groups intact.
__device__ __forceinline__ int swz(int r, int c) {
    return (r * D + c) ^ ((r & 7) << 3);
}

// 4 transposed bf16 weight slices: s<3: ws[s][n][k]=W1[(s*128+k)*128+n]; s==3: W2[k*128+n]
__global__ void prep_weights_kernel(const float* __restrict__ W1,
                                    const float* __restrict__ W2,
                                    bf16_t* __restrict__ ws) {
    int t = blockIdx.x * 256 + threadIdx.x;
    int s = t >> 14, r = t & 16383;
    int n = r >> 7, k = r & 127;
    float v = (s < 3) ? W1[(s * 128 + k) * 128 + n] : W2[k * 128 + n];
    ws[t] = (bf16_t)v;
}

// u = x·W1a + b1, v = x·W1b   (bf16 row-major outputs, gather-ready)
__global__ __launch_bounds__(512, 2)
void uv_kernel(const float* __restrict__ x, const bf16_t* __restrict__ ws,
               const float* __restrict__ b1, bf16_t* __restrict__ u,
               bf16_t* __restrict__ v, int N) {
    extern __shared__ __align__(16) bf16_t lds[];
    const int tid = threadIdx.x, lane = tid & 63, wv = tid >> 6;
    const int col0 = lane & 15, krow = lane >> 4, l31 = lane & 31, half = lane >> 5;
    const int gr = lane >> 4, gc = (lane & 15) * 8;
    const int n0 = blockIdx.x * 256 + wv * 32;
    bf16_t* Ach = lds + 32768 + wv * 4096;

    f32x4 xb[16];
#pragma unroll
    for (int j = 0; j < 16; j++) {
        int node = min(n0 + j * 2 + half, N - 1);
        xb[j] = *(const f32x4*)(x + (long long)node * D + l31 * 4);
    }
#pragma unroll
    for (int s = 0; s < 2; s++)
#pragma unroll
        for (int j = 0; j < 4; j++) {
            int row = j * 32 + (tid >> 4), slot = (tid & 15) * 8;
            bf16x8 w = *(const bf16x8*)(ws + s * 16384 + row * 128 + slot);
            *(bf16x8*)&lds[s * 16384 + swz(row, slot)] = w;
        }
    float bias1[8];
#pragma unroll
    for (int n = 0; n < 8; n++) bias1[n] = b1[n * 16 + col0];
#pragma unroll
    for (int j = 0; j < 16; j++) {
        f32x4 vv = xb[j];
        bf16x4 hv = { (bf16_t)vv.x, (bf16_t)vv.y, (bf16_t)vv.z, (bf16_t)vv.w };
        *(bf16x4*)&Ach[swz(j * 2 + half, l31 * 4)] = hv;
    }
    __syncthreads();

    f32x4 aU[2][8], aV[2][8];
#pragma unroll
    for (int m = 0; m < 2; m++)
#pragma unroll
        for (int n = 0; n < 8; n++) { aU[m][n] = (f32x4){0,0,0,0}; aV[m][n] = (f32x4){0,0,0,0}; }
#pragma unroll
    for (int kk = 0; kk < 4; kk++) {
        bf16x8 a0 = *(const bf16x8*)&Ach[swz(col0, kk*32 + krow*8)];
        bf16x8 a1 = *(const bf16x8*)&Ach[swz(16 + col0, kk*32 + krow*8)];
#pragma unroll
        for (int n = 0; n < 8; n++) {
            bf16x8 bU = *(const bf16x8*)&lds[swz(n*16 + col0, kk*32 + krow*8)];
            bf16x8 bV = *(const bf16x8*)&lds[16384 + swz(n*16 + col0, kk*32 + krow*8)];
            aU[0][n] = __builtin_amdgcn_mfma_f32_16x16x32_bf16(a0, bU, aU[0][n], 0,0,0);
            aU[1][n] = __builtin_amdgcn_mfma_f32_16x16x32_bf16(a1, bU, aU[1][n], 0,0,0);
            aV[0][n] = __builtin_amdgcn_mfma_f32_16x16x32_bf16(a0, bV, aV[0][n], 0,0,0);
            aV[1][n] = __builtin_amdgcn_mfma_f32_16x16x32_bf16(a1, bV, aV[1][n], 0,0,0);
        }
    }
#pragma unroll
    for (int m = 0; m < 2; m++)
#pragma unroll
        for (int n = 0; n < 8; n++)
#pragma unroll
            for (int ri = 0; ri < 4; ri++)
                Ach[swz(m*16 + krow*4 + ri, n*16 + col0)] = (bf16_t)(aU[m][n][ri] + bias1[n]);
#pragma unroll
    for (int j = 0; j < 8; j++) {
        int r = j * 4 + gr, node = n0 + r;
        if (node < N) *(bf16x8*)(u + (long long)node * D + gc) = *(const bf16x8*)&Ach[swz(r, gc)];
    }
#pragma unroll
    for (int m = 0; m < 2; m++)
#pragma unroll
        for (int n = 0; n < 8; n++)
#pragma unroll
            for (int ri = 0; ri < 4; ri++)
                Ach[swz(m*16 + krow*4 + ri, n*16 + col0)] = (bf16_t)(aV[m][n][ri]);
#pragma unroll
    for (int j = 0; j < 8; j++) {
        int r = j * 4 + gr, node = n0 + r;
        if (node < N) *(bf16x8*)(v + (long long)node * D + gc) = *(const bf16x8*)&Ach[swz(r, gc)];
    }
}

// Persistent: out = relu( relu(ea·W1c + u[src] + v[dst]) · W2 + b2 )
// 256 blocks x 8 waves; each wave grid-strides 16-edge groups with loop-carried prefetch.
__global__ __launch_bounds__(512, 1)
void edge_kernel(const bf16_t* __restrict__ u, const bf16_t* __restrict__ v,
                 const float* __restrict__ ea, const int* __restrict__ ei,
                 const bf16_t* __restrict__ ws, const float* __restrict__ b2,
                 float* __restrict__ out, int E) {
    extern __shared__ __align__(16) bf16_t lds[];   // [2][128][128] W1c,W2 + [8][16][128]
    const int tid = threadIdx.x, lane = tid & 63, wv = tid >> 6;
    const int col0 = lane & 15, krow = lane >> 4, l31 = lane & 31, half = lane >> 5;
    const int gr = lane >> 4, gc = (lane & 15) * 8;
    bf16_t* Ach = lds + 32768 + wv * 2048;

    const int totg = (E + 15) >> 4;       // 25000 groups of 16 edges
    const int gstr = gridDim.x * 8;       // 2048 waves
    int g = blockIdx.x * 8 + wv;

    f32x4  eaR[8];
    bf16x8 uR[4], vR[4];
    int sidxN = 0, didxN = 0;

    // ---- prologue: issue group g's loads + prefetch ei(g+1) ----
    if (g < totg) {
        int er = min(g * 16 + col0, E - 1);
        int sidx = ei[er], didx = ei[E + er];
#pragma unroll
        for (int j = 0; j < 8; j++) {
            int e = min(g * 16 + j * 2 + half, E - 1);
            eaR[j] = *(const f32x4*)(ea + (long long)e * D + l31 * 4);
        }
#pragma unroll
        for (int j = 0; j < 4; j++) { int gi = __shfl(sidx, j * 4 + gr); uR[j] = *(const bf16x8*)(u + (long long)gi * D + gc); }
#pragma unroll
        for (int j = 0; j < 4; j++) { int gi = __shfl(didx, j * 4 + gr); vR[j] = *(const bf16x8*)(v + (long long)gi * D + gc); }
        int gn = g + gstr;
        if (gn < totg) {
            int er2 = min(gn * 16 + col0, E - 1);
            sidxN = ei[er2]; didxN = ei[E + er2];
        }
    }
    // stage W1c (slice2), W2 (slice3) once per kernel
#pragma unroll
    for (int s = 0; s < 2; s++)
#pragma unroll
        for (int j = 0; j < 4; j++) {
            int row = j * 32 + (tid >> 4), slot = (tid & 15) * 8;
            bf16x8 w = *(const bf16x8*)(ws + (2 + s) * 16384 + row * 128 + slot);
            *(bf16x8*)&lds[s * 16384 + swz(row, slot)] = w;
        }
    float bias2[8];
#pragma unroll
    for (int n = 0; n < 8; n++) bias2[n] = b2[n * 16 + col0];
    __syncthreads();   // the only barrier

    while (g < totg) {
        const int gn = g + gstr;

        // ea(g) -> chunk (landed ~1 iteration ago)
#pragma unroll
        for (int j = 0; j < 8; j++) {
            f32x4 vv = eaR[j];
            bf16x4 hv = { (bf16_t)vv.x, (bf16_t)vv.y, (bf16_t)vv.z, (bf16_t)vv.w };
            *(bf16x4*)&Ach[swz(j * 2 + half, l31 * 4)] = hv;
        }
        // issue ea(g+1): in flight until next iteration's top
        if (gn < totg) {
#pragma unroll
            for (int j = 0; j < 8; j++) {
                int e = min(gn * 16 + j * 2 + half, E - 1);
                eaR[j] = *(const f32x4*)(ea + (long long)e * D + l31 * 4);
            }
        }
        // prefetch ei(g+2)
        int sidx2 = 0, didx2 = 0;
        int g2 = gn + gstr;
        if (g2 < totg) {
            int er = min(g2 * 16 + col0, E - 1);
            sidx2 = ei[er]; didx2 = ei[E + er];
        }

        // ---- A1: ea · W1c ----
        f32x4 acc[8];
#pragma unroll
        for (int n = 0; n < 8; n++) acc[n] = (f32x4){0,0,0,0};
#pragma unroll
        for (int kk = 0; kk < 4; kk++) {
            bf16x8 a = *(const bf16x8*)&Ach[swz(col0, kk*32 + krow*8)];
#pragma unroll
            for (int n = 0; n < 8; n++) {
                bf16x8 b = *(const bf16x8*)&lds[swz(n*16 + col0, kk*32 + krow*8)];
                acc[n] = __builtin_amdgcn_mfma_f32_16x16x32_bf16(a, b, acc[n], 0, 0, 0);
            }
        }

        // s = u[src]+v[dst] -> chunk (row-space b128 writes; b1 folded into u)
#pragma unroll
        for (int j = 0; j < 4; j++) {
            bf16x8 su = uR[j], sv = vR[j], sr;
#pragma unroll
            for (int t = 0; t < 8; t++) sr[t] = (bf16_t)((float)su[t] + (float)sv[t]);
            *(bf16x8*)&Ach[swz(j * 4 + gr, gc)] = sr;
        }
        // issue u/v(g+1) gathers: in flight until next iteration's s-stage
        if (gn < totg) {
#pragma unroll
            for (int j = 0; j < 4; j++) { int gi = __shfl(sidxN, j * 4 + gr); uR[j] = *(const bf16x8*)(u + (long long)gi * D + gc); }
#pragma unroll
            for (int j = 0; j < 4; j++) { int gi = __shfl(didxN, j * 4 + gr); vR[j] = *(const bf16x8*)(v + (long long)gi * D + gc); }
        }

        // h = relu(acc + s) in C-space, back into chunk as A2's operand
#pragma unroll
        for (int n = 0; n < 8; n++)
#pragma unroll
            for (int ri = 0; ri < 4; ri++) {
                int row = krow * 4 + ri, col = n * 16 + col0;
                float sval = (float)Ach[swz(row, col)];
                float hv = fmaxf(acc[n][ri] + sval, 0.f);
                Ach[swz(row, col)] = (bf16_t)hv;
            }

        // ---- A2: h · W2 ----
#pragma unroll
        for (int n = 0; n < 8; n++) acc[n] = (f32x4){0,0,0,0};
#pragma unroll
        for (int kk = 0; kk < 4; kk++) {
            bf16x8 a = *(const bf16x8*)&Ach[swz(col0, kk*32 + krow*8)];
#pragma unroll
            for (int n = 0; n < 8; n++) {
                bf16x8 b = *(const bf16x8*)&lds[16384 + swz(n*16 + col0, kk*32 + krow*8)];
                acc[n] = __builtin_amdgcn_mfma_f32_16x16x32_bf16(a, b, acc[n], 0, 0, 0);
            }
        }

        // epilogue: out = relu(acc + b2)
#pragma unroll
        for (int n = 0; n < 8; n++)
#pragma unroll
            for (int ri = 0; ri < 4; ri++) {
                int e = g * 16 + krow * 4 + ri;
                if (e < E) out[(long long)e * D + n*16 + col0] = fmaxf(acc[n][ri] + bias2[n], 0.f);
            }

        g = gn; sidxN = sidx2; didxN = didx2;
    }
}

extern "C" void kernel_launch(void* const* d_in, const int* in_sizes, int n_in,
                              void* d_out, int out_size, void* d_ws, size_t ws_size,
                              hipStream_t stream) {
    const float* x  = (const float*)d_in[0];
    const float* ea = (const float*)d_in[1];
    const int*   ei = (const int*)d_in[2];
    const float* W1 = (const float*)d_in[3];
    const float* b1 = (const float*)d_in[4];
    const float* W2 = (const float*)d_in[5];
    const float* b2 = (const float*)d_in[6];
    float* out = (float*)d_out;

    const int E = in_sizes[1] / D;      // 400000
    const int N = in_sizes[0] / D;      // 50000

    bf16_t* wsl = (bf16_t*)d_ws;                  // 128 KB: 4 transposed weight slices
    bf16_t* uu  = wsl + 4 * 16384;                // N*128 bf16
    bf16_t* vv  = uu + (size_t)N * D;             // N*128 bf16

    prep_weights_kernel<<<256, 256, 0, stream>>>(W1, W2, wsl);

    hipFuncSetAttribute(reinterpret_cast<const void*>(uv_kernel),
                        hipFuncAttributeMaxDynamicSharedMemorySize, UV_LDS);
    hipFuncSetAttribute(reinterpret_cast<const void*>(edge_kernel),
                        hipFuncAttributeMaxDynamicSharedMemorySize, EDGE_LDS);

    uv_kernel<<<(N + 255) / 256, 512, UV_LDS, stream>>>(x, wsl, b1, uu, vv, N);

    edge_kernel<<<256, 512, EDGE_LDS, stream>>>(uu, vv, ea, ei, wsl, b2, out, E);
}